// Round 7
// baseline (559.187 us; speedup 1.0000x reference)
//
#include <hip/hip_runtime.h>

#define NN 100000
#define EE 1600000
#define NI4 (EE / 4)              // 400000 int4 records in each of src/dst
#define ROWCAP 64                 // csr slots per node; deg~Poisson(16), P(>64)~1e-21
#define DEGB 128                  // degree-count blocks
#define WTB 48                    // 3 matrices x 16 (32x32) transpose tiles
#define FILLB 512                 // csr sentinel-fill blocks
#define SCB 1024                  // scatter blocks
#define G1B 391                   // gemm blocks (1563 waves of 64 rows)

typedef __attribute__((ext_vector_type(8))) short bf16x8;
typedef __attribute__((ext_vector_type(4))) float f32x4;

// bf16 helpers (exact unpack; RN pack)
__device__ inline unsigned int f2bf2(float a, float b) {  // pack (a=low, b=high)
    unsigned int ua = __float_as_uint(a);
    unsigned int ub = __float_as_uint(b);
    ua = (ua + 0x7fffu + ((ua >> 16) & 1u)) >> 16;
    ub = (ub + 0x7fffu + ((ub >> 16) & 1u)) >> 16;
    return ua | (ub << 16);
}
__device__ inline unsigned short f2bf(float a) {
    unsigned int u = __float_as_uint(a);
    return (unsigned short)((u + 0x7fffu + ((u >> 16) & 1u)) >> 16);
}
__device__ inline float2 bf2f2(unsigned int u) {
    return make_float2(__uint_as_float(u << 16), __uint_as_float(u & 0xffff0000u));
}

// ---------------- K1: deg-count + wt-build + csr sentinel-fill ---------------
// [0,128):   deg-count — coalesced dst4 stream, 4 fire-and-forget atomics/int4
//            (no return value -> wave never stalls on them).
// [128,176): wt transpose-convert via LDS tile, coalesced both ways.
//            Block 128 zeros the hb sentinel row (index NN).
// [176,688): csr sentinel-fill: 6.4M ints of NN, coalesced int4 streams.

__global__ __launch_bounds__(256) void prep1_kernel(const int4* __restrict__ dst4,
                                                    int* __restrict__ deg,
                                                    const float* __restrict__ W1,
                                                    const float* __restrict__ W2,
                                                    const float* __restrict__ W3,
                                                    unsigned short* __restrict__ wt1,
                                                    unsigned short* __restrict__ wt2,
                                                    unsigned short* __restrict__ wt3,
                                                    unsigned int* __restrict__ hb,
                                                    int* __restrict__ csr) {
    __shared__ float tile[32][33];        // 4.2 KB transpose staging
    const int bx = blockIdx.x;

    if (bx < DEGB) {                      // ---- degree-count blocks ----
        const int a0 = bx * (NI4 / DEGB); // 3125 int4 each, exact
        const int a1 = a0 + (NI4 / DEGB);
        for (int i = a0 + threadIdx.x; i < a1; i += 256) {
            int4 d4 = dst4[i];
            atomicAdd(&deg[d4.x], 1);
            atomicAdd(&deg[d4.y], 1);
            atomicAdd(&deg[d4.z], 1);
            atomicAdd(&deg[d4.w], 1);
        }
        return;
    }

    if (bx < DEGB + WTB) {                // ---- wt-build blocks ----
        const int wb = bx - DEGB;
        const int m = wb >> 4;            // matrix 0..2
        const int tl = wb & 15;           // 32x32 tile
        const int ti = tl >> 2, tj = tl & 3;   // k-tile, n-tile
        const float* W = m == 0 ? W1 : (m == 1 ? W2 : W3);
        unsigned short* wt = m == 0 ? wt1 : (m == 1 ? wt2 : wt3);
        const int r = threadIdx.x >> 5, c = threadIdx.x & 31;
#pragma unroll
        for (int rr = r; rr < 32; rr += 8)     // coalesced read of W[k][n]
            tile[rr][c] = W[(ti * 32 + rr) * 128 + tj * 32 + c];
        __syncthreads();
#pragma unroll
        for (int rr = r; rr < 32; rr += 8)     // coalesced write of wt[n][k]
            wt[(size_t)(tj * 32 + rr) * 128 + ti * 32 + c] = f2bf(tile[c][rr]);
        if (wb == 0 && threadIdx.x < 64) hb[(size_t)NN * 64 + threadIdx.x] = 0;
        return;
    }

    // ---- csr sentinel-fill blocks ----
    const int fb = bx - DEGB - WTB;                 // 0..511
    int4* c4 = (int4*)csr;                          // 1.6M int4 total
    const int a0 = fb * ((NN * ROWCAP / 4) / FILLB);// 3125 int4 each, exact
    const int a1 = a0 + ((NN * ROWCAP / 4) / FILLB);
    const int4 sv = make_int4(NN, NN, NN, NN);
    for (int i = a0 + threadIdx.x; i < a1; i += 256) c4[i] = sv;
}

// ---------------- GEMM body: hs(bf16) = dinv[row] * (x @ W) via MFMA ---------
// 64 rows per wave (4 tiles of 16), W-fragments hoisted ONCE into registers.
// (256,2) -> 256-VGPR cap, no spill (round-5 lesson: never starve MFMA regs).

template <bool F32IN>
__device__ __forceinline__ void gemm_body(int wave, const void* __restrict__ xin,
                                          const unsigned short* __restrict__ wt,
                                          const int* __restrict__ deg,
                                          unsigned int* __restrict__ hb) {
    const int base = wave * 64;
    if (base >= NN) return;
    const int lane = threadIdx.x & 63;
    const int r = lane & 15;
    const int q = lane >> 4;
    const unsigned short* wrow = wt + (size_t)r * 128 + q * 8;
    bf16x8 wfr[4][8];
#pragma unroll
    for (int kc = 0; kc < 4; ++kc)
#pragma unroll
        for (int nt = 0; nt < 8; ++nt)
            wfr[kc][nt] = *(const bf16x8*)(wrow + (size_t)nt * 16 * 128 + kc * 32);
#pragma unroll
    for (int tt = 0; tt < 4; ++tt) {
        const int m0 = base + tt * 16;
        if (m0 >= NN) break;
        f32x4 acc[8] = {};
#pragma unroll
        for (int kc = 0; kc < 4; ++kc) {
            bf16x8 xf;
            if (F32IN) {
                const float* xrow = (const float*)xin + (size_t)(m0 + r) * 128 + q * 8 + kc * 32;
                float4 a = *(const float4*)xrow;
                float4 b = *(const float4*)(xrow + 4);
                unsigned short tmp[8] = {f2bf(a.x), f2bf(a.y), f2bf(a.z), f2bf(a.w),
                                         f2bf(b.x), f2bf(b.y), f2bf(b.z), f2bf(b.w)};
                xf = *(const bf16x8*)tmp;
            } else {
                const unsigned short* xrow =
                    (const unsigned short*)xin + (size_t)(m0 + r) * 128 + q * 8 + kc * 32;
                xf = *(const bf16x8*)xrow;
            }
#pragma unroll
            for (int nt = 0; nt < 8; ++nt)
                acc[nt] = __builtin_amdgcn_mfma_f32_16x16x32_bf16(wfr[kc][nt], xf, acc[nt], 0, 0, 0);
        }
        const int orow = m0 + r;
        const float dvr = rsqrtf(1.0f + (float)deg[orow]);
        unsigned int* hrow = hb + (size_t)orow * 64;  // uint = 2 bf16
#pragma unroll
        for (int nt = 0; nt < 8; ++nt) {
            int n = nt * 16 + q * 4;
            *(uint2*)(hrow + (n >> 1)) =
                make_uint2(f2bf2(acc[nt][0] * dvr, acc[nt][1] * dvr),
                           f2bf2(acc[nt][2] * dvr, acc[nt][3] * dvr));
        }
    }
}

// ---------------- K2: scatter-CSR (blocks 0-1023) + layer-1 GEMM -------------
// scatter: pos = atomicAdd(cur[d]); csr[d*64+pos] = s. Row slots beyond cur[d]
// keep the K1 sentinel (NN -> zero hb row). gemm1 depends only on deg/wt1/x0
// (all complete after K1) -> cost hidden under the scatter. No LDS in K2.

__global__ __launch_bounds__(256, 2) void scatter_gemm1_kernel(const int4* __restrict__ src4,
                                                               const int4* __restrict__ dst4,
                                                               int* __restrict__ cur,
                                                               int* __restrict__ csr,
                                                               const float* __restrict__ x0,
                                                               const unsigned short* __restrict__ wt1,
                                                               const int* __restrict__ deg,
                                                               unsigned int* __restrict__ hb) {
    if (blockIdx.x < SCB) {               // ---- scatter blocks ----
        for (int i = blockIdx.x * 256 + threadIdx.x; i < NI4; i += SCB * 256) {
            int4 d4 = dst4[i];
            int4 s4 = src4[i];
            int p0 = atomicAdd(&cur[d4.x], 1);
            int p1 = atomicAdd(&cur[d4.y], 1);
            int p2 = atomicAdd(&cur[d4.z], 1);
            int p3 = atomicAdd(&cur[d4.w], 1);
            csr[(d4.x << 6) + p0] = s4.x;
            csr[(d4.y << 6) + p1] = s4.y;
            csr[(d4.z << 6) + p2] = s4.z;
            csr[(d4.w << 6) + p3] = s4.w;
        }
        return;
    }
    const int wave = (blockIdx.x - SCB) * 4 + (threadIdx.x >> 6);
    gemm_body<true>(wave, (const void*)x0, wt1, deg, hb);
}

// standalone GEMM for layers 2/3
template <bool F32IN>
__global__ __launch_bounds__(256, 2) void gemm_kernel(const void* __restrict__ xin,
                                                      const unsigned short* __restrict__ wt,
                                                      const int* __restrict__ deg,
                                                      unsigned int* __restrict__ hb) {
    const int wave = blockIdx.x * 4 + (threadIdx.x >> 6);
    gemm_body<F32IN>(wave, xin, wt, deg, hb);
}

// ---------------- aggregation: out[d] = relu( dv*(hs[d] + sum_e hs[src_e]) + b )
// Round-0 measured form (62.6 us @ 3.96 TB/s): one node per wave, 4 waves per
// block, fresh waves (no grid-stride). Row base is now d*64, length from deg[],
// padded region holds sentinel NN (zero hs row). dv = rsqrtf(1+deg) inline.

template <bool BF16OUT>
__global__ __launch_bounds__(256) void aggregate_kernel(const unsigned int* __restrict__ hb,
                                                        const int* __restrict__ csr,
                                                        const int* __restrict__ deg,
                                                        const float2* __restrict__ bias2,
                                                        void* __restrict__ outp) {
    const int d = blockIdx.x * 4 + (threadIdx.x >> 6);
    const int j = threadIdx.x & 63;     // lane
    const int dg = deg[d];
    int e = d << 6;                     // row base in csr
    const int end = e + ((dg + 7) & ~7);
    float2 acc = bf2f2(hb[(size_t)d * 64 + j]);   // self term: hs[d]
    for (; e + 16 <= end; e += 16) {
        int4 c0 = *(const int4*)(csr + e);
        int4 c1 = *(const int4*)(csr + e + 4);
        int4 c2 = *(const int4*)(csr + e + 8);
        int4 c3 = *(const int4*)(csr + e + 12);
        unsigned int v0 = hb[(size_t)c0.x * 64 + j];
        unsigned int v1 = hb[(size_t)c0.y * 64 + j];
        unsigned int v2 = hb[(size_t)c0.z * 64 + j];
        unsigned int v3 = hb[(size_t)c0.w * 64 + j];
        unsigned int v4 = hb[(size_t)c1.x * 64 + j];
        unsigned int v5 = hb[(size_t)c1.y * 64 + j];
        unsigned int v6 = hb[(size_t)c1.z * 64 + j];
        unsigned int v7 = hb[(size_t)c1.w * 64 + j];
        unsigned int v8 = hb[(size_t)c2.x * 64 + j];
        unsigned int v9 = hb[(size_t)c2.y * 64 + j];
        unsigned int va = hb[(size_t)c2.z * 64 + j];
        unsigned int vb = hb[(size_t)c2.w * 64 + j];
        unsigned int vc = hb[(size_t)c3.x * 64 + j];
        unsigned int vd = hb[(size_t)c3.y * 64 + j];
        unsigned int ve = hb[(size_t)c3.z * 64 + j];
        unsigned int vf = hb[(size_t)c3.w * 64 + j];
        float2 f0 = bf2f2(v0), f1 = bf2f2(v1), f2 = bf2f2(v2), f3 = bf2f2(v3);
        float2 f4 = bf2f2(v4), f5 = bf2f2(v5), f6 = bf2f2(v6), f7 = bf2f2(v7);
        float2 f8 = bf2f2(v8), f9 = bf2f2(v9), fa = bf2f2(va), fb = bf2f2(vb);
        float2 fc = bf2f2(vc), fd = bf2f2(vd), fe = bf2f2(ve), ff = bf2f2(vf);
        acc.x += ((f0.x + f1.x) + (f2.x + f3.x)) + ((f4.x + f5.x) + (f6.x + f7.x)) +
                 ((f8.x + f9.x) + (fa.x + fb.x)) + ((fc.x + fd.x) + (fe.x + ff.x));
        acc.y += ((f0.y + f1.y) + (f2.y + f3.y)) + ((f4.y + f5.y) + (f6.y + f7.y)) +
                 ((f8.y + f9.y) + (fa.y + fb.y)) + ((fc.y + fd.y) + (fe.y + ff.y));
    }
    if (e < end) {  // one trailing 8-batch
        int4 c0 = *(const int4*)(csr + e);
        int4 c1 = *(const int4*)(csr + e + 4);
        unsigned int v0 = hb[(size_t)c0.x * 64 + j];
        unsigned int v1 = hb[(size_t)c0.y * 64 + j];
        unsigned int v2 = hb[(size_t)c0.z * 64 + j];
        unsigned int v3 = hb[(size_t)c0.w * 64 + j];
        unsigned int v4 = hb[(size_t)c1.x * 64 + j];
        unsigned int v5 = hb[(size_t)c1.y * 64 + j];
        unsigned int v6 = hb[(size_t)c1.z * 64 + j];
        unsigned int v7 = hb[(size_t)c1.w * 64 + j];
        float2 f0 = bf2f2(v0), f1 = bf2f2(v1), f2 = bf2f2(v2), f3 = bf2f2(v3);
        float2 f4 = bf2f2(v4), f5 = bf2f2(v5), f6 = bf2f2(v6), f7 = bf2f2(v7);
        acc.x += ((f0.x + f1.x) + (f2.x + f3.x)) + ((f4.x + f5.x) + (f6.x + f7.x));
        acc.y += ((f0.y + f1.y) + (f2.y + f3.y)) + ((f4.y + f5.y) + (f6.y + f7.y));
    }
    const float dv = rsqrtf(1.0f + (float)dg);
    float2 bb = bias2[j];
    float ox = fmaxf(dv * acc.x + bb.x, 0.0f);
    float oy = fmaxf(dv * acc.y + bb.y, 0.0f);
    if (BF16OUT) {
        ((unsigned int*)outp)[(size_t)d * 64 + j] = f2bf2(ox, oy);
    } else {
        ((float2*)outp)[(size_t)d * 64 + j] = make_float2(ox, oy);
    }
}

// ---------------- launch ----------------

extern "C" void kernel_launch(void* const* d_in, const int* in_sizes, int n_in,
                              void* d_out, int out_size, void* d_ws, size_t ws_size,
                              hipStream_t stream) {
    const float* x0 = (const float*)d_in[0];
    const int* ei = (const int*)d_in[1];   // int32 on device (harness contract)
    const float* W1 = (const float*)d_in[2];
    const float* b1 = (const float*)d_in[3];
    const float* W2 = (const float*)d_in[4];
    const float* b2 = (const float*)d_in[5];
    const float* W3 = (const float*)d_in[6];
    const float* b3 = (const float*)d_in[7];
    float* out = (float*)d_out;

    char* ws = (char*)d_ws;
    size_t off = 0;
    auto alloc = [&](size_t bytes) -> void* {
        off = (off + 511) & ~(size_t)511;
        void* p = ws + off;
        off += bytes;
        return p;
    };
    unsigned int* hb = (unsigned int*)alloc(((size_t)NN + 1) * 64 * 4);   // 25.6 MB hs (+ zero row)
    int* csr = (int*)alloc((size_t)NN * ROWCAP * sizeof(int));            // 25.6 MB
    int* deg = (int*)alloc((size_t)NN * sizeof(int));
    int* cur = (int*)alloc((size_t)NN * sizeof(int));
    unsigned short* wt1 = (unsigned short*)alloc(128 * 128 * 2);
    unsigned short* wt2 = (unsigned short*)alloc(128 * 128 * 2);
    unsigned short* wt3 = (unsigned short*)alloc(128 * 128 * 2);

    // bf16 activation ping buffer for layers 1-2 lives in d_out's first 25.6 MB
    unsigned int* xact = (unsigned int*)d_out;

    const int4* src4 = (const int4*)ei;          // edge_index[0]
    const int4* dst4 = (const int4*)(ei + EE);   // edge_index[1]

    // graph prep (redone every call: ws is re-poisoned)
    hipMemsetAsync(deg, 0, (size_t)NN * sizeof(int), stream);
    hipMemsetAsync(cur, 0, (size_t)NN * sizeof(int), stream);
    prep1_kernel<<<DEGB + WTB + FILLB, 256, 0, stream>>>(dst4, deg, W1, W2, W3,
                                                         wt1, wt2, wt3, hb, csr);
    scatter_gemm1_kernel<<<SCB + G1B, 256, 0, stream>>>(src4, dst4, cur, csr,
                                                        x0, wt1, deg, hb);
    aggregate_kernel<true><<<NN / 4, 256, 0, stream>>>(hb, csr, deg,
                                                       (const float2*)b1, (void*)xact);
    gemm_kernel<false><<<G1B, 256, 0, stream>>>((const void*)xact, wt2, deg, hb);
    aggregate_kernel<true><<<NN / 4, 256, 0, stream>>>(hb, csr, deg,
                                                       (const float2*)b2, (void*)xact);
    gemm_kernel<false><<<G1B, 256, 0, stream>>>((const void*)xact, wt3, deg, hb);
    aggregate_kernel<false><<<NN / 4, 256, 0, stream>>>(hb, csr, deg,
                                                        (const float2*)b3, (void*)out);
}

// Round 8
// 491.479 us; speedup vs baseline: 1.1378x; 1.1378x over previous
//
#include <hip/hip_runtime.h>

#define NN 100000
#define EE 1600000
#define NPART 8                   // dst-space partitions
#define PSZ (NN / NPART)          // 12500 nodes per partition
#define NI4 (EE / 4)              // 400000 int4 records in dst/src
#define SUBW 196                  // dst nodes per sub-bucket (64 per partition)
#define NSB (NPART * 64)          // 512 sub-buckets
#define SCAP 4096                 // records per sub-bucket (exp 3136, +17 sigma)
#define RCAP 8192                 // staged slots per sub-bucket (exp ~3960)
#define LBCAP 96                  // LDS bin capacity (round-0 proven)
#define ROWCAP 64                 // csr slots per node; P(deg>64) ~ 1e-21
#define WTB 48                    // 3 matrices x 16 (32x32) transpose tiles

typedef __attribute__((ext_vector_type(8))) short bf16x8;
typedef __attribute__((ext_vector_type(4))) float f32x4;

// bf16 helpers (exact unpack; RN pack)
__device__ inline unsigned int f2bf2(float a, float b) {  // pack (a=low, b=high)
    unsigned int ua = __float_as_uint(a);
    unsigned int ub = __float_as_uint(b);
    ua = (ua + 0x7fffu + ((ua >> 16) & 1u)) >> 16;
    ub = (ub + 0x7fffu + ((ub >> 16) & 1u)) >> 16;
    return ua | (ub << 16);
}
__device__ inline unsigned short f2bf(float a) {
    unsigned int u = __float_as_uint(a);
    return (unsigned short)((u + 0x7fffu + ((u >> 16) & 1u)) >> 16);
}
__device__ inline float2 bf2f2(unsigned int u) {
    return make_float2(__uint_as_float(u << 16), __uint_as_float(u & 0xffff0000u));
}

// ---------------- K1: wt-build (blocks 0-47) + round-0 filterbin (48-559) ----
// No deg atomics anywhere (rounds 4/6: they cost ~20 us in any placement).
// Block 0 also zeros the hb sentinel row and dinv[NN] (sentinel edges -> +0).

__global__ __launch_bounds__(256) void fbwt_kernel(const int4* __restrict__ src4,
                                                   const int4* __restrict__ dst4,
                                                   int* __restrict__ gcur2,
                                                   uint2* __restrict__ buckets2,
                                                   const float* __restrict__ W1,
                                                   const float* __restrict__ W2,
                                                   const float* __restrict__ W3,
                                                   unsigned short* __restrict__ wt1,
                                                   unsigned short* __restrict__ wt2,
                                                   unsigned short* __restrict__ wt3,
                                                   unsigned int* __restrict__ hb,
                                                   float* __restrict__ dinv) {
    __shared__ uint2 bins[64][LBCAP];
    __shared__ int bcnt[64];
    __shared__ int gbase[64];
    __shared__ float tile[32][33];
    const int bx = blockIdx.x;

    if (bx < WTB) {                       // ---- wt-build blocks ----
        const int m = bx >> 4;            // matrix 0..2
        const int tl = bx & 15;           // 32x32 tile
        const int ti = tl >> 2, tj = tl & 3;
        const float* W = m == 0 ? W1 : (m == 1 ? W2 : W3);
        unsigned short* wt = m == 0 ? wt1 : (m == 1 ? wt2 : wt3);
        const int r = threadIdx.x >> 5, c = threadIdx.x & 31;
#pragma unroll
        for (int rr = r; rr < 32; rr += 8)     // coalesced read of W[k][n]
            tile[rr][c] = W[(ti * 32 + rr) * 128 + tj * 32 + c];
        __syncthreads();
#pragma unroll
        for (int rr = r; rr < 32; rr += 8)     // coalesced write of wt[n][k]
            wt[(size_t)(tj * 32 + rr) * 128 + ti * 32 + c] = f2bf(tile[c][rr]);
        if (bx == 0) {
            if (threadIdx.x < 64) hb[(size_t)NN * 64 + threadIdx.x] = 0;
            if (threadIdx.x == 64) dinv[NN] = 0.0f;
        }
        return;
    }

    // ---- filter blocks (round-0 exact config: 512 blocks, LBCAP 96) ----
    const int fb = bx - WTB;
    const int p = fb >> 6;
    const int c = fb & 63;
    if (threadIdx.x < 64) bcnt[threadIdx.x] = 0;
    __syncthreads();
    const int lo = p * PSZ, hi = lo + PSZ;
    const int chunk4 = NI4 / 64;                    // 6250, exact
    const int a0 = c * chunk4, a1 = a0 + chunk4;
    for (int i = a0 + threadIdx.x; i < a1; i += 256) {
        int4 d4 = dst4[i];
        bool m0 = (d4.x >= lo && d4.x < hi);
        bool m1 = (d4.y >= lo && d4.y < hi);
        bool m2 = (d4.z >= lo && d4.z < hi);
        bool m3 = (d4.w >= lo && d4.w < hi);
        if (!(m0 | m1 | m2 | m3)) continue;
        int4 s4 = src4[i];
        int ss[4] = {s4.x, s4.y, s4.z, s4.w};
        int dd[4] = {d4.x, d4.y, d4.z, d4.w};
        bool mm[4] = {m0, m1, m2, m3};
#pragma unroll
        for (int k = 0; k < 4; ++k) {
            if (!mm[k]) continue;
            int li = (dd[k] - lo) / SUBW;           // 0..63
            int pos = atomicAdd(&bcnt[li], 1);
            if (pos < LBCAP) {
                bins[li][pos] = make_uint2((unsigned)ss[k], (unsigned)dd[k]);
            } else {                                 // rare overflow: direct append
                int sb = p * 64 + li;
                int gp = atomicAdd(&gcur2[sb], 1);
                buckets2[(size_t)sb * SCAP + gp] = make_uint2((unsigned)ss[k], (unsigned)dd[k]);
            }
        }
    }
    __syncthreads();
    if (threadIdx.x < 64) {
        int cc = min(bcnt[threadIdx.x], LBCAP);
        gbase[threadIdx.x] = atomicAdd(&gcur2[p * 64 + threadIdx.x], cc);
        bcnt[threadIdx.x] = cc;
    }
    __syncthreads();
    for (int b = 0; b < 64; ++b) {
        const int cc = bcnt[b];
        uint2* outp = buckets2 + (size_t)(p * 64 + b) * SCAP + gbase[b];
        for (int i = threadIdx.x; i < cc; i += 256) outp[i] = bins[b][i];
    }
}

// ---------------- GEMM body: hs(bf16) = x @ W via MFMA (RAW, no scaling) -----
// 64 rows per wave, W-fragments hoisted once into registers. (256,2): 256-VGPR
// cap, no spill (round-5 lesson). dinv scaling moved into the aggregate.

template <bool F32IN>
__device__ __forceinline__ void gemm_body(int wave, const void* __restrict__ xin,
                                          const unsigned short* __restrict__ wt,
                                          unsigned int* __restrict__ hb) {
    const int base = wave * 64;
    if (base >= NN) return;
    const int lane = threadIdx.x & 63;
    const int r = lane & 15;
    const int q = lane >> 4;
    const unsigned short* wrow = wt + (size_t)r * 128 + q * 8;
    bf16x8 wfr[4][8];
#pragma unroll
    for (int kc = 0; kc < 4; ++kc)
#pragma unroll
        for (int nt = 0; nt < 8; ++nt)
            wfr[kc][nt] = *(const bf16x8*)(wrow + (size_t)nt * 16 * 128 + kc * 32);
#pragma unroll
    for (int tt = 0; tt < 4; ++tt) {
        const int m0 = base + tt * 16;
        if (m0 >= NN) break;
        f32x4 acc[8] = {};
#pragma unroll
        for (int kc = 0; kc < 4; ++kc) {
            bf16x8 xf;
            if (F32IN) {
                const float* xrow = (const float*)xin + (size_t)(m0 + r) * 128 + q * 8 + kc * 32;
                float4 a = *(const float4*)xrow;
                float4 b = *(const float4*)(xrow + 4);
                unsigned short tmp[8] = {f2bf(a.x), f2bf(a.y), f2bf(a.z), f2bf(a.w),
                                         f2bf(b.x), f2bf(b.y), f2bf(b.z), f2bf(b.w)};
                xf = *(const bf16x8*)tmp;
            } else {
                const unsigned short* xrow =
                    (const unsigned short*)xin + (size_t)(m0 + r) * 128 + q * 8 + kc * 32;
                xf = *(const bf16x8*)xrow;
            }
#pragma unroll
            for (int nt = 0; nt < 8; ++nt)
                acc[nt] = __builtin_amdgcn_mfma_f32_16x16x32_bf16(wfr[kc][nt], xf, acc[nt], 0, 0, 0);
        }
        const int orow = m0 + r;
        unsigned int* hrow = hb + (size_t)orow * 64;  // uint = 2 bf16
#pragma unroll
        for (int nt = 0; nt < 8; ++nt) {
            int n = nt * 16 + q * 4;
            *(uint2*)(hrow + (n >> 1)) =
                make_uint2(f2bf2(acc[nt][0], acc[nt][1]), f2bf2(acc[nt][2], acc[nt][3]));
        }
    }
}

// ---------------- K2: sort3 (blocks 0-511) + layer-1 GEMM (512-902) ----------
// sort3 now emits FIXED-STRIDE rows: csr[d*64 .. d*64+63], sentinel-padded
// (slot >= padded deg holds NN -> zero hb row, dinv[NN]=0). gemm1 needs only
// wt1/x0 (complete after K1) -> fully hidden under sort3. Emits deg[], dinv[].

__global__ __launch_bounds__(256, 2) void sort3_gemm1_kernel(const uint2* __restrict__ buckets2,
                                                             const int* __restrict__ gcur2,
                                                             int* __restrict__ csr,
                                                             int* __restrict__ deg,
                                                             float* __restrict__ dinv,
                                                             const float* __restrict__ x0,
                                                             const unsigned short* __restrict__ wt1,
                                                             unsigned int* __restrict__ hb) {
    __shared__ int hist[256];
    __shared__ int pscan[256];
    __shared__ int lcur[256];
    __shared__ int rs[256];
    __shared__ int staged[RCAP];
    if (blockIdx.x >= 512) {   // layer-1 GEMM blocks
        const int wave = (blockIdx.x - 512) * 4 + (threadIdx.x >> 6);
        gemm_body<true>(wave, (const void*)x0, wt1, hb);
        return;
    }
    const int sb = blockIdx.x;
    const int li = sb & 63;
    const int base_node = (sb >> 6) * PSZ + li * SUBW;
    const int nnodes = min(SUBW, PSZ - li * SUBW);  // 196 (152 for last)
    const int scnt = gcur2[sb];
    const uint2* bk = buckets2 + (size_t)sb * SCAP;
    const int t = threadIdx.x;
    hist[t] = 0;
    __syncthreads();
    for (int i = t; i < scnt; i += 256) atomicAdd(&hist[(int)bk[i].y - base_node], 1);
    __syncthreads();
    const int padded = (t < nnodes) ? ((hist[t] + 7) & ~7) : 0;
    pscan[t] = padded;
    __syncthreads();
    for (int off = 1; off < 256; off <<= 1) {
        int v = (t >= off) ? pscan[t - off] : 0;
        __syncthreads();
        pscan[t] += v;
        __syncthreads();
    }
    const int rstart = pscan[t] - padded;           // exclusive scan
    lcur[t] = rstart;
    rs[t] = rstart;
    __syncthreads();
    const int total = pscan[255];                   // multiple of 8
    for (int i = t; i < total; i += 256) staged[i] = NN;  // sentinel fill
    __syncthreads();
    for (int i = t; i < scnt; i += 256) {
        uint2 r = bk[i];
        int pos = atomicAdd(&lcur[(int)r.y - base_node], 1);
        staged[pos] = (int)r.x;
    }
    __syncthreads();
    // write-out: fixed 16 int4 per node (64 slots), sentinel beyond padded deg
    const int4* staged4 = (const int4*)staged;
    int4* csr4 = (int4*)csr;
    const int4 sv = make_int4(NN, NN, NN, NN);
    for (int i = t; i < nnodes * 16; i += 256) {
        const int n = i >> 4, s = i & 15;
        const int pad = (hist[n] + 7) & ~7;
        int4 v = (s * 4 < pad) ? staged4[(rs[n] >> 2) + s] : sv;
        csr4[((size_t)(base_node + n) << 4) + s] = v;
    }
    if (t < nnodes) {
        int dg = hist[t];
        deg[base_node + t] = dg;
        dinv[base_node + t] = rsqrtf(1.0f + (float)dg);
    }
}

// standalone GEMM for layers 2/3
template <bool F32IN>
__global__ __launch_bounds__(256, 2) void gemm_kernel(const void* __restrict__ xin,
                                                      const unsigned short* __restrict__ wt,
                                                      unsigned int* __restrict__ hb) {
    const int wave = blockIdx.x * 4 + (threadIdx.x >> 6);
    gemm_body<F32IN>(wave, xin, wt, hb);
}

// ---------------- aggregation ------------------------------------------------
// out[d] = relu( dinv[d] * ( dinv[d]*h[d] + sum_e dinv[src]*h[src] ) + b )
// One node per wave (round-0 proven), fixed-stride row d*64. 32 slots gathered
// UNCONDITIONALLY (2x16 batches in flight; sentinel slots hit the hot zero row
// + dinv[NN]=0). Rare deg>32 handled by tail loop. Per-edge dinv fma: table is
// 400KB -> L2-resident broadcast loads.

#define GATH4(c, v0, v1, v2, v3, w0, w1, w2, w3)                              \
    unsigned int v0 = hb[(size_t)(c).x * 64 + j], v1 = hb[(size_t)(c).y * 64 + j], \
                 v2 = hb[(size_t)(c).z * 64 + j], v3 = hb[(size_t)(c).w * 64 + j]; \
    float w0 = dinv[(c).x], w1 = dinv[(c).y], w2 = dinv[(c).z], w3 = dinv[(c).w];

#define ACC4(v0, v1, v2, v3, w0, w1, w2, w3)                                  \
    {                                                                         \
        float2 f0 = bf2f2(v0), f1 = bf2f2(v1), f2 = bf2f2(v2), f3 = bf2f2(v3);\
        acc.x += (w0 * f0.x + w1 * f1.x) + (w2 * f2.x + w3 * f3.x);           \
        acc.y += (w0 * f0.y + w1 * f1.y) + (w2 * f2.y + w3 * f3.y);           \
    }

template <bool BF16OUT>
__global__ __launch_bounds__(256) void aggregate_kernel(const unsigned int* __restrict__ hb,
                                                        const int* __restrict__ csr,
                                                        const int* __restrict__ deg,
                                                        const float* __restrict__ dinv,
                                                        const float2* __restrict__ bias2,
                                                        void* __restrict__ outp) {
    const int d = blockIdx.x * 4 + (threadIdx.x >> 6);
    const int j = threadIdx.x & 63;     // lane
    const int dg = deg[d];
    const float dv = dinv[d];
    const int4* crow = (const int4*)(csr + ((size_t)d << 6));
    float2 acc;
    {   // self term: dinv[d]*h[d]
        float2 s = bf2f2(hb[(size_t)d * 64 + j]);
        acc.x = dv * s.x;
        acc.y = dv * s.y;
    }
    // unconditional 32-slot gather, issued as 8 groups before any consume
    int4 c0 = crow[0], c1 = crow[1], c2 = crow[2], c3 = crow[3];
    int4 c4 = crow[4], c5 = crow[5], c6 = crow[6], c7 = crow[7];
    GATH4(c0, va0, va1, va2, va3, wa0, wa1, wa2, wa3)
    GATH4(c1, vb0, vb1, vb2, vb3, wb0, wb1, wb2, wb3)
    GATH4(c2, vc0, vc1, vc2, vc3, wc0, wc1, wc2, wc3)
    GATH4(c3, vd0, vd1, vd2, vd3, wd0, wd1, wd2, wd3)
    GATH4(c4, ve0, ve1, ve2, ve3, we0, we1, we2, we3)
    GATH4(c5, vf0, vf1, vf2, vf3, wf0, wf1, wf2, wf3)
    GATH4(c6, vg0, vg1, vg2, vg3, wg0, wg1, wg2, wg3)
    GATH4(c7, vh0, vh1, vh2, vh3, wh0, wh1, wh2, wh3)
    ACC4(va0, va1, va2, va3, wa0, wa1, wa2, wa3)
    ACC4(vb0, vb1, vb2, vb3, wb0, wb1, wb2, wb3)
    ACC4(vc0, vc1, vc2, vc3, wc0, wc1, wc2, wc3)
    ACC4(vd0, vd1, vd2, vd3, wd0, wd1, wd2, wd3)
    ACC4(ve0, ve1, ve2, ve3, we0, we1, we2, we3)
    ACC4(vf0, vf1, vf2, vf3, wf0, wf1, wf2, wf3)
    ACC4(vg0, vg1, vg2, vg3, wg0, wg1, wg2, wg3)
    ACC4(vh0, vh1, vh2, vh3, wh0, wh1, wh2, wh3)
    // rare tail: 32 < padded deg <= 64
    const int padded = min((dg + 7) & ~7, ROWCAP);
    for (int e = 32; e < padded; e += 8) {
        int4 t0 = crow[e >> 2], t1 = crow[(e >> 2) + 1];
        GATH4(t0, x0, x1, x2, x3, y0, y1, y2, y3)
        GATH4(t1, x4, x5, x6, x7, y4, y5, y6, y7)
        ACC4(x0, x1, x2, x3, y0, y1, y2, y3)
        ACC4(x4, x5, x6, x7, y4, y5, y6, y7)
    }
    float2 bb = bias2[j];
    float ox = fmaxf(dv * acc.x + bb.x, 0.0f);
    float oy = fmaxf(dv * acc.y + bb.y, 0.0f);
    if (BF16OUT) {
        ((unsigned int*)outp)[(size_t)d * 64 + j] = f2bf2(ox, oy);
    } else {
        ((float2*)outp)[(size_t)d * 64 + j] = make_float2(ox, oy);
    }
}

// ---------------- launch ----------------

extern "C" void kernel_launch(void* const* d_in, const int* in_sizes, int n_in,
                              void* d_out, int out_size, void* d_ws, size_t ws_size,
                              hipStream_t stream) {
    const float* x0 = (const float*)d_in[0];
    const int* ei = (const int*)d_in[1];   // int32 on device (harness contract)
    const float* W1 = (const float*)d_in[2];
    const float* b1 = (const float*)d_in[3];
    const float* W2 = (const float*)d_in[4];
    const float* b2 = (const float*)d_in[5];
    const float* W3 = (const float*)d_in[6];
    const float* b3 = (const float*)d_in[7];
    float* out = (float*)d_out;

    char* ws = (char*)d_ws;
    size_t off = 0;
    auto alloc = [&](size_t bytes) -> void* {
        off = (off + 511) & ~(size_t)511;
        void* p = ws + off;
        off += bytes;
        return p;
    };
    unsigned int* hb = (unsigned int*)alloc(((size_t)NN + 1) * 64 * 4);   // 25.6 MB (+ zero row)
    int* csr = (int*)alloc((size_t)NN * ROWCAP * sizeof(int));            // 25.6 MB fixed-stride
    uint2* buckets2 = (uint2*)alloc((size_t)NSB * SCAP * sizeof(uint2));  // 16.8 MB
    int* deg = (int*)alloc((size_t)NN * sizeof(int));
    float* dinv = (float*)alloc(((size_t)NN + 1) * sizeof(float));        // + sentinel 0
    int* gcur2 = (int*)alloc(NSB * sizeof(int));
    unsigned short* wt1 = (unsigned short*)alloc(128 * 128 * 2);
    unsigned short* wt2 = (unsigned short*)alloc(128 * 128 * 2);
    unsigned short* wt3 = (unsigned short*)alloc(128 * 128 * 2);

    // bf16 activation ping buffer for layers 1-2 lives in d_out's first 25.6 MB
    unsigned int* xact = (unsigned int*)d_out;

    const int4* src4 = (const int4*)ei;          // edge_index[0]
    const int4* dst4 = (const int4*)(ei + EE);   // edge_index[1]

    // graph prep (redone every call: ws is re-poisoned)
    hipMemsetAsync(gcur2, 0, NSB * sizeof(int), stream);
    fbwt_kernel<<<WTB + 512, 256, 0, stream>>>(src4, dst4, gcur2, buckets2,
                                               W1, W2, W3, wt1, wt2, wt3, hb, dinv);
    sort3_gemm1_kernel<<<903, 256, 0, stream>>>(buckets2, gcur2, csr, deg, dinv,
                                                x0, wt1, hb);
    aggregate_kernel<true><<<NN / 4, 256, 0, stream>>>(hb, csr, deg, dinv,
                                                       (const float2*)b1, (void*)xact);
    gemm_kernel<false><<<391, 256, 0, stream>>>((const void*)xact, wt2, hb);
    aggregate_kernel<true><<<NN / 4, 256, 0, stream>>>(hb, csr, deg, dinv,
                                                       (const float2*)b2, (void*)xact);
    gemm_kernel<false><<<391, 256, 0, stream>>>((const void*)xact, wt3, hb);
    aggregate_kernel<false><<<NN / 4, 256, 0, stream>>>(hb, csr, deg, dinv,
                                                        (const float2*)b3, (void*)out);
}

// Round 9
// 411.522 us; speedup vs baseline: 1.3588x; 1.1943x over previous
//
#include <hip/hip_runtime.h>

#define NN 100000
#define EE 1600000
#define NPART 8                   // dst-space partitions
#define PSZ (NN / NPART)          // 12500 nodes per partition
#define NI4 (EE / 4)              // 400000 int4 records in dst/src
#define SUBW 196                  // dst nodes per sub-bucket (64 per partition)
#define NSB (NPART * 64)          // 512 sub-buckets
#define SCAP 4096                 // records per sub-bucket (exp 3136, +17 sigma)
#define RCAP 8192                 // staged slots per sub-bucket (exp ~3960)
#define LBCAP 96                  // LDS bin capacity (round-0 proven)
#define ROWCAP 64                 // csr slots per node; P(deg>64) ~ 1e-21
#define WTB 48                    // 3 matrices x 16 (32x32) transpose tiles

typedef __attribute__((ext_vector_type(8))) short bf16x8;
typedef __attribute__((ext_vector_type(4))) float f32x4;

// bf16 helpers (exact unpack; RN pack)
__device__ inline unsigned int f2bf2(float a, float b) {  // pack (a=low, b=high)
    unsigned int ua = __float_as_uint(a);
    unsigned int ub = __float_as_uint(b);
    ua = (ua + 0x7fffu + ((ua >> 16) & 1u)) >> 16;
    ub = (ub + 0x7fffu + ((ub >> 16) & 1u)) >> 16;
    return ua | (ub << 16);
}
__device__ inline unsigned short f2bf(float a) {
    unsigned int u = __float_as_uint(a);
    return (unsigned short)((u + 0x7fffu + ((u >> 16) & 1u)) >> 16);
}
__device__ inline float2 bf2f2(unsigned int u) {
    return make_float2(__uint_as_float(u << 16), __uint_as_float(u & 0xffff0000u));
}

// ---------------- K1: wt-build (blocks 0-47) + round-0 filterbin (48-559) ----
// Lean: no deg atomics (rounds 4/6: ~20 us in any placement). Block 0 zeros
// the hb sentinel row and dinv[NN].

__global__ __launch_bounds__(256) void fbwt_kernel(const int4* __restrict__ src4,
                                                   const int4* __restrict__ dst4,
                                                   int* __restrict__ gcur2,
                                                   uint2* __restrict__ buckets2,
                                                   const float* __restrict__ W1,
                                                   const float* __restrict__ W2,
                                                   const float* __restrict__ W3,
                                                   unsigned short* __restrict__ wt1,
                                                   unsigned short* __restrict__ wt2,
                                                   unsigned short* __restrict__ wt3,
                                                   unsigned int* __restrict__ hb,
                                                   float* __restrict__ dinv) {
    __shared__ uint2 bins[64][LBCAP];
    __shared__ int bcnt[64];
    __shared__ int gbase[64];
    __shared__ float tile[32][33];
    const int bx = blockIdx.x;

    if (bx < WTB) {                       // ---- wt-build blocks ----
        const int m = bx >> 4;            // matrix 0..2
        const int tl = bx & 15;           // 32x32 tile
        const int ti = tl >> 2, tj = tl & 3;
        const float* W = m == 0 ? W1 : (m == 1 ? W2 : W3);
        unsigned short* wt = m == 0 ? wt1 : (m == 1 ? wt2 : wt3);
        const int r = threadIdx.x >> 5, c = threadIdx.x & 31;
#pragma unroll
        for (int rr = r; rr < 32; rr += 8)     // coalesced read of W[k][n]
            tile[rr][c] = W[(ti * 32 + rr) * 128 + tj * 32 + c];
        __syncthreads();
#pragma unroll
        for (int rr = r; rr < 32; rr += 8)     // coalesced write of wt[n][k]
            wt[(size_t)(tj * 32 + rr) * 128 + ti * 32 + c] = f2bf(tile[c][rr]);
        if (bx == 0) {
            if (threadIdx.x < 64) hb[(size_t)NN * 64 + threadIdx.x] = 0;
            if (threadIdx.x == 64) dinv[NN] = 0.0f;
        }
        return;
    }

    // ---- filter blocks (round-0 exact config: 512 blocks, LBCAP 96) ----
    const int fb = bx - WTB;
    const int p = fb >> 6;
    const int c = fb & 63;
    if (threadIdx.x < 64) bcnt[threadIdx.x] = 0;
    __syncthreads();
    const int lo = p * PSZ, hi = lo + PSZ;
    const int chunk4 = NI4 / 64;                    // 6250, exact
    const int a0 = c * chunk4, a1 = a0 + chunk4;
    for (int i = a0 + threadIdx.x; i < a1; i += 256) {
        int4 d4 = dst4[i];
        bool m0 = (d4.x >= lo && d4.x < hi);
        bool m1 = (d4.y >= lo && d4.y < hi);
        bool m2 = (d4.z >= lo && d4.z < hi);
        bool m3 = (d4.w >= lo && d4.w < hi);
        if (!(m0 | m1 | m2 | m3)) continue;
        int4 s4 = src4[i];
        int ss[4] = {s4.x, s4.y, s4.z, s4.w};
        int dd[4] = {d4.x, d4.y, d4.z, d4.w};
        bool mm[4] = {m0, m1, m2, m3};
#pragma unroll
        for (int k = 0; k < 4; ++k) {
            if (!mm[k]) continue;
            int li = (dd[k] - lo) / SUBW;           // 0..63
            int pos = atomicAdd(&bcnt[li], 1);
            if (pos < LBCAP) {
                bins[li][pos] = make_uint2((unsigned)ss[k], (unsigned)dd[k]);
            } else {                                 // rare overflow: direct append
                int sb = p * 64 + li;
                int gp = atomicAdd(&gcur2[sb], 1);
                buckets2[(size_t)sb * SCAP + gp] = make_uint2((unsigned)ss[k], (unsigned)dd[k]);
            }
        }
    }
    __syncthreads();
    if (threadIdx.x < 64) {
        int cc = min(bcnt[threadIdx.x], LBCAP);
        gbase[threadIdx.x] = atomicAdd(&gcur2[p * 64 + threadIdx.x], cc);
        bcnt[threadIdx.x] = cc;
    }
    __syncthreads();
    for (int b = 0; b < 64; ++b) {
        const int cc = bcnt[b];
        uint2* outp = buckets2 + (size_t)(p * 64 + b) * SCAP + gbase[b];
        for (int i = threadIdx.x; i < cc; i += 256) outp[i] = bins[b][i];
    }
}

// ---------------- GEMM body: hb(bf16) = [dinv[row] *] (x @ W) via MFMA -------
// 64 rows per wave, W-fragments hoisted once into registers. (256,2): 256-VGPR
// cap, no spill. SCALE=false for layer 1 (dinv not ready -> raw h; aggregate 1
// applies weights); SCALE=true for layers 2/3 (round-0 exact math).

template <bool F32IN, bool SCALE>
__device__ __forceinline__ void gemm_body(int wave, const void* __restrict__ xin,
                                          const unsigned short* __restrict__ wt,
                                          const float* __restrict__ dinv,
                                          unsigned int* __restrict__ hb) {
    const int base = wave * 64;
    if (base >= NN) return;
    const int lane = threadIdx.x & 63;
    const int r = lane & 15;
    const int q = lane >> 4;
    const unsigned short* wrow = wt + (size_t)r * 128 + q * 8;
    bf16x8 wfr[4][8];
#pragma unroll
    for (int kc = 0; kc < 4; ++kc)
#pragma unroll
        for (int nt = 0; nt < 8; ++nt)
            wfr[kc][nt] = *(const bf16x8*)(wrow + (size_t)nt * 16 * 128 + kc * 32);
#pragma unroll
    for (int tt = 0; tt < 4; ++tt) {
        const int m0 = base + tt * 16;
        if (m0 >= NN) break;
        f32x4 acc[8] = {};
#pragma unroll
        for (int kc = 0; kc < 4; ++kc) {
            bf16x8 xf;
            if (F32IN) {
                const float* xrow = (const float*)xin + (size_t)(m0 + r) * 128 + q * 8 + kc * 32;
                float4 a = *(const float4*)xrow;
                float4 b = *(const float4*)(xrow + 4);
                unsigned short tmp[8] = {f2bf(a.x), f2bf(a.y), f2bf(a.z), f2bf(a.w),
                                         f2bf(b.x), f2bf(b.y), f2bf(b.z), f2bf(b.w)};
                xf = *(const bf16x8*)tmp;
            } else {
                const unsigned short* xrow =
                    (const unsigned short*)xin + (size_t)(m0 + r) * 128 + q * 8 + kc * 32;
                xf = *(const bf16x8*)xrow;
            }
#pragma unroll
            for (int nt = 0; nt < 8; ++nt)
                acc[nt] = __builtin_amdgcn_mfma_f32_16x16x32_bf16(wfr[kc][nt], xf, acc[nt], 0, 0, 0);
        }
        const int orow = m0 + r;
        const float dvr = SCALE ? dinv[orow] : 1.0f;
        unsigned int* hrow = hb + (size_t)orow * 64;  // uint = 2 bf16
#pragma unroll
        for (int nt = 0; nt < 8; ++nt) {
            int n = nt * 16 + q * 4;
            if (SCALE) {
                *(uint2*)(hrow + (n >> 1)) =
                    make_uint2(f2bf2(acc[nt][0] * dvr, acc[nt][1] * dvr),
                               f2bf2(acc[nt][2] * dvr, acc[nt][3] * dvr));
            } else {
                *(uint2*)(hrow + (n >> 1)) =
                    make_uint2(f2bf2(acc[nt][0], acc[nt][1]), f2bf2(acc[nt][2], acc[nt][3]));
            }
        }
    }
}

// ---------------- K2: sort3 (blocks 0-511) + layer-1 GEMM (512-902) ----------
// sort3 emits FIXED-STRIDE rows csr[d*64..], sentinel-padded, + deg[], dinv[].
// gemm1 needs only wt1/x0 (complete after K1) -> fully hidden under sort3.

__global__ __launch_bounds__(256, 2) void sort3_gemm1_kernel(const uint2* __restrict__ buckets2,
                                                             const int* __restrict__ gcur2,
                                                             int* __restrict__ csr,
                                                             int* __restrict__ deg,
                                                             float* __restrict__ dinv,
                                                             const float* __restrict__ x0,
                                                             const unsigned short* __restrict__ wt1,
                                                             unsigned int* __restrict__ hb) {
    __shared__ int hist[256];
    __shared__ int pscan[256];
    __shared__ int lcur[256];
    __shared__ int rs[256];
    __shared__ int staged[RCAP];
    if (blockIdx.x >= 512) {   // layer-1 GEMM blocks (raw output)
        const int wave = (blockIdx.x - 512) * 4 + (threadIdx.x >> 6);
        gemm_body<true, false>(wave, (const void*)x0, wt1, nullptr, hb);
        return;
    }
    const int sb = blockIdx.x;
    const int li = sb & 63;
    const int base_node = (sb >> 6) * PSZ + li * SUBW;
    const int nnodes = min(SUBW, PSZ - li * SUBW);  // 196 (152 for last)
    const int scnt = gcur2[sb];
    const uint2* bk = buckets2 + (size_t)sb * SCAP;
    const int t = threadIdx.x;
    hist[t] = 0;
    __syncthreads();
    for (int i = t; i < scnt; i += 256) atomicAdd(&hist[(int)bk[i].y - base_node], 1);
    __syncthreads();
    const int padded = (t < nnodes) ? ((hist[t] + 7) & ~7) : 0;
    pscan[t] = padded;
    __syncthreads();
    for (int off = 1; off < 256; off <<= 1) {
        int v = (t >= off) ? pscan[t - off] : 0;
        __syncthreads();
        pscan[t] += v;
        __syncthreads();
    }
    const int rstart = pscan[t] - padded;           // exclusive scan
    lcur[t] = rstart;
    rs[t] = rstart;
    __syncthreads();
    const int total = pscan[255];                   // multiple of 8
    for (int i = t; i < total; i += 256) staged[i] = NN;  // sentinel fill
    __syncthreads();
    for (int i = t; i < scnt; i += 256) {
        uint2 r = bk[i];
        int pos = atomicAdd(&lcur[(int)r.y - base_node], 1);
        staged[pos] = (int)r.x;
    }
    __syncthreads();
    // write-out: fixed 16 int4 per node (64 slots), sentinel beyond padded deg
    const int4* staged4 = (const int4*)staged;
    int4* csr4 = (int4*)csr;
    const int4 sv = make_int4(NN, NN, NN, NN);
    for (int i = t; i < nnodes * 16; i += 256) {
        const int n = i >> 4, s = i & 15;
        const int pad = (hist[n] + 7) & ~7;
        int4 v = (s * 4 < pad) ? staged4[(rs[n] >> 2) + s] : sv;
        csr4[((size_t)(base_node + n) << 4) + s] = v;
    }
    if (t < nnodes) {
        int dg = hist[t];
        deg[base_node + t] = dg;
        dinv[base_node + t] = rsqrtf(1.0f + (float)dg);
    }
}

// standalone GEMM for layers 2/3 (dinv ready -> scaled epilogue, round-0 exact)
__global__ __launch_bounds__(256, 2) void gemm_kernel(const void* __restrict__ xin,
                                                      const unsigned short* __restrict__ wt,
                                                      const float* __restrict__ dinv,
                                                      unsigned int* __restrict__ hb) {
    const int wave = blockIdx.x * 4 + (threadIdx.x >> 6);
    gemm_body<false, true>(wave, xin, wt, dinv, hb);
}

// ---------------- aggregation ------------------------------------------------
// Round-0 measured loop (one node per wave, variable-length 16-batches), rows
// at fixed stride d*64, length from deg[]. WEIGHTED (layer 1 only): hb holds
// raw h, gather applies dinv[src] fma + self dinv[d] (dinv L2-resident).
// !WEIGHTED (layers 2/3): hb holds pre-scaled hs, pure adds (round-0 exact).

template <bool BF16OUT, bool WEIGHTED>
__global__ __launch_bounds__(256) void aggregate_kernel(const unsigned int* __restrict__ hb,
                                                        const int* __restrict__ csr,
                                                        const int* __restrict__ deg,
                                                        const float* __restrict__ dinv,
                                                        const float2* __restrict__ bias2,
                                                        void* __restrict__ outp) {
    const int d = blockIdx.x * 4 + (threadIdx.x >> 6);
    const int j = threadIdx.x & 63;     // lane
    const int dg = deg[d];
    const float dv = dinv[d];
    int e = d << 6;                     // fixed-stride row base
    const int end = e + ((dg + 7) & ~7);
    float2 acc;
    {   // self term
        float2 s = bf2f2(hb[(size_t)d * 64 + j]);
        if (WEIGHTED) { acc.x = dv * s.x; acc.y = dv * s.y; }
        else          { acc.x = s.x;      acc.y = s.y; }
    }
    for (; e + 16 <= end; e += 16) {
        int4 c0 = *(const int4*)(csr + e);
        int4 c1 = *(const int4*)(csr + e + 4);
        int4 c2 = *(const int4*)(csr + e + 8);
        int4 c3 = *(const int4*)(csr + e + 12);
        unsigned int v0 = hb[(size_t)c0.x * 64 + j];
        unsigned int v1 = hb[(size_t)c0.y * 64 + j];
        unsigned int v2 = hb[(size_t)c0.z * 64 + j];
        unsigned int v3 = hb[(size_t)c0.w * 64 + j];
        unsigned int v4 = hb[(size_t)c1.x * 64 + j];
        unsigned int v5 = hb[(size_t)c1.y * 64 + j];
        unsigned int v6 = hb[(size_t)c1.z * 64 + j];
        unsigned int v7 = hb[(size_t)c1.w * 64 + j];
        unsigned int v8 = hb[(size_t)c2.x * 64 + j];
        unsigned int v9 = hb[(size_t)c2.y * 64 + j];
        unsigned int va = hb[(size_t)c2.z * 64 + j];
        unsigned int vb = hb[(size_t)c2.w * 64 + j];
        unsigned int vc = hb[(size_t)c3.x * 64 + j];
        unsigned int vd = hb[(size_t)c3.y * 64 + j];
        unsigned int ve = hb[(size_t)c3.z * 64 + j];
        unsigned int vf = hb[(size_t)c3.w * 64 + j];
        float2 f0 = bf2f2(v0), f1 = bf2f2(v1), f2 = bf2f2(v2), f3 = bf2f2(v3);
        float2 f4 = bf2f2(v4), f5 = bf2f2(v5), f6 = bf2f2(v6), f7 = bf2f2(v7);
        float2 f8 = bf2f2(v8), f9 = bf2f2(v9), fa = bf2f2(va), fb = bf2f2(vb);
        float2 fc = bf2f2(vc), fd = bf2f2(vd), fe = bf2f2(ve), ff = bf2f2(vf);
        if (WEIGHTED) {
            float w0 = dinv[c0.x], w1 = dinv[c0.y], w2 = dinv[c0.z], w3 = dinv[c0.w];
            float w4 = dinv[c1.x], w5 = dinv[c1.y], w6 = dinv[c1.z], w7 = dinv[c1.w];
            float w8 = dinv[c2.x], w9 = dinv[c2.y], wa = dinv[c2.z], wb = dinv[c2.w];
            float wc = dinv[c3.x], wd = dinv[c3.y], we = dinv[c3.z], wf = dinv[c3.w];
            acc.x += ((w0 * f0.x + w1 * f1.x) + (w2 * f2.x + w3 * f3.x)) +
                     ((w4 * f4.x + w5 * f5.x) + (w6 * f6.x + w7 * f7.x)) +
                     ((w8 * f8.x + w9 * f9.x) + (wa * fa.x + wb * fb.x)) +
                     ((wc * fc.x + wd * fd.x) + (we * fe.x + wf * ff.x));
            acc.y += ((w0 * f0.y + w1 * f1.y) + (w2 * f2.y + w3 * f3.y)) +
                     ((w4 * f4.y + w5 * f5.y) + (w6 * f6.y + w7 * f7.y)) +
                     ((w8 * f8.y + w9 * f9.y) + (wa * fa.y + wb * fb.y)) +
                     ((wc * fc.y + wd * fd.y) + (we * fe.y + wf * ff.y));
        } else {
            acc.x += ((f0.x + f1.x) + (f2.x + f3.x)) + ((f4.x + f5.x) + (f6.x + f7.x)) +
                     ((f8.x + f9.x) + (fa.x + fb.x)) + ((fc.x + fd.x) + (fe.x + ff.x));
            acc.y += ((f0.y + f1.y) + (f2.y + f3.y)) + ((f4.y + f5.y) + (f6.y + f7.y)) +
                     ((f8.y + f9.y) + (fa.y + fb.y)) + ((fc.y + fd.y) + (fe.y + ff.y));
        }
    }
    if (e < end) {  // one trailing 8-batch
        int4 c0 = *(const int4*)(csr + e);
        int4 c1 = *(const int4*)(csr + e + 4);
        unsigned int v0 = hb[(size_t)c0.x * 64 + j];
        unsigned int v1 = hb[(size_t)c0.y * 64 + j];
        unsigned int v2 = hb[(size_t)c0.z * 64 + j];
        unsigned int v3 = hb[(size_t)c0.w * 64 + j];
        unsigned int v4 = hb[(size_t)c1.x * 64 + j];
        unsigned int v5 = hb[(size_t)c1.y * 64 + j];
        unsigned int v6 = hb[(size_t)c1.z * 64 + j];
        unsigned int v7 = hb[(size_t)c1.w * 64 + j];
        float2 f0 = bf2f2(v0), f1 = bf2f2(v1), f2 = bf2f2(v2), f3 = bf2f2(v3);
        float2 f4 = bf2f2(v4), f5 = bf2f2(v5), f6 = bf2f2(v6), f7 = bf2f2(v7);
        if (WEIGHTED) {
            float w0 = dinv[c0.x], w1 = dinv[c0.y], w2 = dinv[c0.z], w3 = dinv[c0.w];
            float w4 = dinv[c1.x], w5 = dinv[c1.y], w6 = dinv[c1.z], w7 = dinv[c1.w];
            acc.x += ((w0 * f0.x + w1 * f1.x) + (w2 * f2.x + w3 * f3.x)) +
                     ((w4 * f4.x + w5 * f5.x) + (w6 * f6.x + w7 * f7.x));
            acc.y += ((w0 * f0.y + w1 * f1.y) + (w2 * f2.y + w3 * f3.y)) +
                     ((w4 * f4.y + w5 * f5.y) + (w6 * f6.y + w7 * f7.y));
        } else {
            acc.x += ((f0.x + f1.x) + (f2.x + f3.x)) + ((f4.x + f5.x) + (f6.x + f7.x));
            acc.y += ((f0.y + f1.y) + (f2.y + f3.y)) + ((f4.y + f5.y) + (f6.y + f7.y));
        }
    }
    float2 bb = bias2[j];
    float ox = fmaxf(dv * acc.x + bb.x, 0.0f);
    float oy = fmaxf(dv * acc.y + bb.y, 0.0f);
    if (BF16OUT) {
        ((unsigned int*)outp)[(size_t)d * 64 + j] = f2bf2(ox, oy);
    } else {
        ((float2*)outp)[(size_t)d * 64 + j] = make_float2(ox, oy);
    }
}

// ---------------- launch ----------------

extern "C" void kernel_launch(void* const* d_in, const int* in_sizes, int n_in,
                              void* d_out, int out_size, void* d_ws, size_t ws_size,
                              hipStream_t stream) {
    const float* x0 = (const float*)d_in[0];
    const int* ei = (const int*)d_in[1];   // int32 on device (harness contract)
    const float* W1 = (const float*)d_in[2];
    const float* b1 = (const float*)d_in[3];
    const float* W2 = (const float*)d_in[4];
    const float* b2 = (const float*)d_in[5];
    const float* W3 = (const float*)d_in[6];
    const float* b3 = (const float*)d_in[7];
    float* out = (float*)d_out;

    char* ws = (char*)d_ws;
    size_t off = 0;
    auto alloc = [&](size_t bytes) -> void* {
        off = (off + 511) & ~(size_t)511;
        void* p = ws + off;
        off += bytes;
        return p;
    };
    unsigned int* hb = (unsigned int*)alloc(((size_t)NN + 1) * 64 * 4);   // 25.6 MB (+ zero row)
    int* csr = (int*)alloc((size_t)NN * ROWCAP * sizeof(int));            // 25.6 MB fixed-stride
    uint2* buckets2 = (uint2*)alloc((size_t)NSB * SCAP * sizeof(uint2));  // 16.8 MB
    int* deg = (int*)alloc((size_t)NN * sizeof(int));
    float* dinv = (float*)alloc(((size_t)NN + 1) * sizeof(float));        // + sentinel 0
    int* gcur2 = (int*)alloc(NSB * sizeof(int));
    unsigned short* wt1 = (unsigned short*)alloc(128 * 128 * 2);
    unsigned short* wt2 = (unsigned short*)alloc(128 * 128 * 2);
    unsigned short* wt3 = (unsigned short*)alloc(128 * 128 * 2);

    // bf16 activation ping buffer for layers 1-2 lives in d_out's first 25.6 MB
    unsigned int* xact = (unsigned int*)d_out;

    const int4* src4 = (const int4*)ei;          // edge_index[0]
    const int4* dst4 = (const int4*)(ei + EE);   // edge_index[1]

    // graph prep (redone every call: ws is re-poisoned)
    hipMemsetAsync(gcur2, 0, NSB * sizeof(int), stream);
    fbwt_kernel<<<WTB + 512, 256, 0, stream>>>(src4, dst4, gcur2, buckets2,
                                               W1, W2, W3, wt1, wt2, wt3, hb, dinv);
    sort3_gemm1_kernel<<<903, 256, 0, stream>>>(buckets2, gcur2, csr, deg, dinv,
                                                x0, wt1, hb);
    // layer 1: raw h in hb -> weighted aggregate
    aggregate_kernel<true, true><<<NN / 4, 256, 0, stream>>>(hb, csr, deg, dinv,
                                                             (const float2*)b1, (void*)xact);
    // layer 2: scaled GEMM epilogue -> round-0 aggregate
    gemm_kernel<<<391, 256, 0, stream>>>((const void*)xact, wt2, dinv, hb);
    aggregate_kernel<true, false><<<NN / 4, 256, 0, stream>>>(hb, csr, deg, dinv,
                                                              (const float2*)b2, (void*)xact);
    // layer 3
    gemm_kernel<<<391, 256, 0, stream>>>((const void*)xact, wt3, dinv, hb);
    aggregate_kernel<false, false><<<NN / 4, 256, 0, stream>>>(hb, csr, deg, dinv,
                                                               (const float2*)b3, (void*)out);
}

// Round 10
// 398.604 us; speedup vs baseline: 1.4029x; 1.0324x over previous
//
#include <hip/hip_runtime.h>

#define NN 100000
#define EE 1600000
#define NPART 8                   // dst-space partitions
#define PSZ (NN / NPART)          // 12500 nodes per partition
#define NI4 (EE / 4)              // 400000 int4 records in dst/src
#define SUBW 196                  // dst nodes per sub-bucket (64 per partition)
#define NSB (NPART * 64)          // 512 sub-buckets
#define SCAP 4096                 // records per sub-bucket (exp 3136, +17 sigma)
#define RCAP 8192                 // csr slots per sub-bucket region (exp ~3960)
#define LBCAP 96                  // LDS bin capacity (round-0 proven)
#define WTB 48                    // 3 matrices x 16 (32x32) transpose tiles

typedef __attribute__((ext_vector_type(8))) short bf16x8;
typedef __attribute__((ext_vector_type(4))) float f32x4;

// bf16 helpers (exact unpack; RN pack)
__device__ inline unsigned int f2bf2(float a, float b) {  // pack (a=low, b=high)
    unsigned int ua = __float_as_uint(a);
    unsigned int ub = __float_as_uint(b);
    ua = (ua + 0x7fffu + ((ua >> 16) & 1u)) >> 16;
    ub = (ub + 0x7fffu + ((ub >> 16) & 1u)) >> 16;
    return ua | (ub << 16);
}
__device__ inline unsigned short f2bf(float a) {
    unsigned int u = __float_as_uint(a);
    return (unsigned short)((u + 0x7fffu + ((u >> 16) & 1u)) >> 16);
}
__device__ inline float2 bf2f2(unsigned int u) {
    return make_float2(__uint_as_float(u << 16), __uint_as_float(u & 0xffff0000u));
}

// ---------------- K1: wt-build (blocks 0-47) + round-0 filterbin (48-559) ----
// Lean: no deg atomics (rounds 4/6: ~20 us in any placement). Block 0 zeros
// the hb sentinel row and dinv[NN].

__global__ __launch_bounds__(256) void fbwt_kernel(const int4* __restrict__ src4,
                                                   const int4* __restrict__ dst4,
                                                   int* __restrict__ gcur2,
                                                   uint2* __restrict__ buckets2,
                                                   const float* __restrict__ W1,
                                                   const float* __restrict__ W2,
                                                   const float* __restrict__ W3,
                                                   unsigned short* __restrict__ wt1,
                                                   unsigned short* __restrict__ wt2,
                                                   unsigned short* __restrict__ wt3,
                                                   unsigned int* __restrict__ hb,
                                                   float* __restrict__ dinv) {
    __shared__ uint2 bins[64][LBCAP];
    __shared__ int bcnt[64];
    __shared__ int gbase[64];
    __shared__ float tile[32][33];
    const int bx = blockIdx.x;

    if (bx < WTB) {                       // ---- wt-build blocks ----
        const int m = bx >> 4;            // matrix 0..2
        const int tl = bx & 15;           // 32x32 tile
        const int ti = tl >> 2, tj = tl & 3;
        const float* W = m == 0 ? W1 : (m == 1 ? W2 : W3);
        unsigned short* wt = m == 0 ? wt1 : (m == 1 ? wt2 : wt3);
        const int r = threadIdx.x >> 5, c = threadIdx.x & 31;
#pragma unroll
        for (int rr = r; rr < 32; rr += 8)     // coalesced read of W[k][n]
            tile[rr][c] = W[(ti * 32 + rr) * 128 + tj * 32 + c];
        __syncthreads();
#pragma unroll
        for (int rr = r; rr < 32; rr += 8)     // coalesced write of wt[n][k]
            wt[(size_t)(tj * 32 + rr) * 128 + ti * 32 + c] = f2bf(tile[c][rr]);
        if (bx == 0) {
            if (threadIdx.x < 64) hb[(size_t)NN * 64 + threadIdx.x] = 0;
            if (threadIdx.x == 64) dinv[NN] = 0.0f;
        }
        return;
    }

    // ---- filter blocks (round-0 exact config: 512 blocks, LBCAP 96) ----
    const int fb = bx - WTB;
    const int p = fb >> 6;
    const int c = fb & 63;
    if (threadIdx.x < 64) bcnt[threadIdx.x] = 0;
    __syncthreads();
    const int lo = p * PSZ, hi = lo + PSZ;
    const int chunk4 = NI4 / 64;                    // 6250, exact
    const int a0 = c * chunk4, a1 = a0 + chunk4;
    for (int i = a0 + threadIdx.x; i < a1; i += 256) {
        int4 d4 = dst4[i];
        bool m0 = (d4.x >= lo && d4.x < hi);
        bool m1 = (d4.y >= lo && d4.y < hi);
        bool m2 = (d4.z >= lo && d4.z < hi);
        bool m3 = (d4.w >= lo && d4.w < hi);
        if (!(m0 | m1 | m2 | m3)) continue;
        int4 s4 = src4[i];
        int ss[4] = {s4.x, s4.y, s4.z, s4.w};
        int dd[4] = {d4.x, d4.y, d4.z, d4.w};
        bool mm[4] = {m0, m1, m2, m3};
#pragma unroll
        for (int k = 0; k < 4; ++k) {
            if (!mm[k]) continue;
            int li = (dd[k] - lo) / SUBW;           // 0..63
            int pos = atomicAdd(&bcnt[li], 1);
            if (pos < LBCAP) {
                bins[li][pos] = make_uint2((unsigned)ss[k], (unsigned)dd[k]);
            } else {                                 // rare overflow: direct append
                int sb = p * 64 + li;
                int gp = atomicAdd(&gcur2[sb], 1);
                buckets2[(size_t)sb * SCAP + gp] = make_uint2((unsigned)ss[k], (unsigned)dd[k]);
            }
        }
    }
    __syncthreads();
    if (threadIdx.x < 64) {
        int cc = min(bcnt[threadIdx.x], LBCAP);
        gbase[threadIdx.x] = atomicAdd(&gcur2[p * 64 + threadIdx.x], cc);
        bcnt[threadIdx.x] = cc;
    }
    __syncthreads();
    for (int b = 0; b < 64; ++b) {
        const int cc = bcnt[b];
        uint2* outp = buckets2 + (size_t)(p * 64 + b) * SCAP + gbase[b];
        for (int i = threadIdx.x; i < cc; i += 256) outp[i] = bins[b][i];
    }
}

// ---------------- GEMM body: hb(bf16) = [dinv[row] *] (x @ W) via MFMA -------
// 64 rows per wave, W-fragments hoisted once into registers. (256,2): 256-VGPR
// cap, no spill. SCALE=false for layer 1 (dinv not ready -> raw h; aggregate 1
// applies weights); SCALE=true for layers 2/3 (round-0 exact math).

template <bool F32IN, bool SCALE>
__device__ __forceinline__ void gemm_body(int wave, const void* __restrict__ xin,
                                          const unsigned short* __restrict__ wt,
                                          const float* __restrict__ dinv,
                                          unsigned int* __restrict__ hb) {
    const int base = wave * 64;
    if (base >= NN) return;
    const int lane = threadIdx.x & 63;
    const int r = lane & 15;
    const int q = lane >> 4;
    const unsigned short* wrow = wt + (size_t)r * 128 + q * 8;
    bf16x8 wfr[4][8];
#pragma unroll
    for (int kc = 0; kc < 4; ++kc)
#pragma unroll
        for (int nt = 0; nt < 8; ++nt)
            wfr[kc][nt] = *(const bf16x8*)(wrow + (size_t)nt * 16 * 128 + kc * 32);
#pragma unroll
    for (int tt = 0; tt < 4; ++tt) {
        const int m0 = base + tt * 16;
        if (m0 >= NN) break;
        f32x4 acc[8] = {};
#pragma unroll
        for (int kc = 0; kc < 4; ++kc) {
            bf16x8 xf;
            if (F32IN) {
                const float* xrow = (const float*)xin + (size_t)(m0 + r) * 128 + q * 8 + kc * 32;
                float4 a = *(const float4*)xrow;
                float4 b = *(const float4*)(xrow + 4);
                unsigned short tmp[8] = {f2bf(a.x), f2bf(a.y), f2bf(a.z), f2bf(a.w),
                                         f2bf(b.x), f2bf(b.y), f2bf(b.z), f2bf(b.w)};
                xf = *(const bf16x8*)tmp;
            } else {
                const unsigned short* xrow =
                    (const unsigned short*)xin + (size_t)(m0 + r) * 128 + q * 8 + kc * 32;
                xf = *(const bf16x8*)xrow;
            }
#pragma unroll
            for (int nt = 0; nt < 8; ++nt)
                acc[nt] = __builtin_amdgcn_mfma_f32_16x16x32_bf16(wfr[kc][nt], xf, acc[nt], 0, 0, 0);
        }
        const int orow = m0 + r;
        const float dvr = SCALE ? dinv[orow] : 1.0f;
        unsigned int* hrow = hb + (size_t)orow * 64;  // uint = 2 bf16
#pragma unroll
        for (int nt = 0; nt < 8; ++nt) {
            int n = nt * 16 + q * 4;
            if (SCALE) {
                *(uint2*)(hrow + (n >> 1)) =
                    make_uint2(f2bf2(acc[nt][0] * dvr, acc[nt][1] * dvr),
                               f2bf2(acc[nt][2] * dvr, acc[nt][3] * dvr));
            } else {
                *(uint2*)(hrow + (n >> 1)) =
                    make_uint2(f2bf2(acc[nt][0], acc[nt][1]), f2bf2(acc[nt][2], acc[nt][3]));
            }
        }
    }
}

// ---------------- K2: sort3 (blocks 0-511) + layer-1 GEMM (512-902) ----------
// ROUND-0 EXACT sort3: compact padded rows in csr[sb*RCAP + rstart], one
// coalesced int4 stream write, info[d] = (rowoff<<8)|deg, dinv[d]. (Round-9's
// fixed-stride rows cost ~11 us per aggregate -- reverted.) gemm1 needs only
// wt1/x0 (complete after K1) -> fully hidden under sort3.

__global__ __launch_bounds__(256, 2) void sort3_gemm1_kernel(const uint2* __restrict__ buckets2,
                                                             const int* __restrict__ gcur2,
                                                             int* __restrict__ csr,
                                                             int* __restrict__ info,
                                                             float* __restrict__ dinv,
                                                             const float* __restrict__ x0,
                                                             const unsigned short* __restrict__ wt1,
                                                             unsigned int* __restrict__ hb) {
    __shared__ int hist[256];
    __shared__ int pscan[256];
    __shared__ int lcur[256];
    __shared__ int staged[RCAP];
    if (blockIdx.x >= 512) {   // layer-1 GEMM blocks (raw output)
        const int wave = (blockIdx.x - 512) * 4 + (threadIdx.x >> 6);
        gemm_body<true, false>(wave, (const void*)x0, wt1, nullptr, hb);
        return;
    }
    const int sb = blockIdx.x;
    const int li = sb & 63;
    const int base_node = (sb >> 6) * PSZ + li * SUBW;
    const int nnodes = min(SUBW, PSZ - li * SUBW);  // 196 (152 for last)
    const int scnt = gcur2[sb];
    const uint2* bk = buckets2 + (size_t)sb * SCAP;
    const int t = threadIdx.x;
    hist[t] = 0;
    __syncthreads();
    for (int i = t; i < scnt; i += 256) atomicAdd(&hist[(int)bk[i].y - base_node], 1);
    __syncthreads();
    const int padded = (t < nnodes) ? ((hist[t] + 7) & ~7) : 0;
    pscan[t] = padded;
    __syncthreads();
    for (int off = 1; off < 256; off <<= 1) {
        int v = (t >= off) ? pscan[t - off] : 0;
        __syncthreads();
        pscan[t] += v;
        __syncthreads();
    }
    const int rstart = pscan[t] - padded;           // exclusive scan
    lcur[t] = rstart;
    __syncthreads();
    const int total = pscan[255];                   // multiple of 8
    for (int i = t; i < total; i += 256) staged[i] = NN;  // sentinel fill
    __syncthreads();
    for (int i = t; i < scnt; i += 256) {
        uint2 r = bk[i];
        int pos = atomicAdd(&lcur[(int)r.y - base_node], 1);
        staged[pos] = (int)r.x;
    }
    __syncthreads();
    int4* co = (int4*)(csr + (size_t)sb * RCAP);
    for (int i = t; i < (total >> 2); i += 256) co[i] = ((const int4*)staged)[i];
    if (t < nnodes) {
        int dg = hist[t];
        info[base_node + t] = ((sb * RCAP + rstart) << 8) | dg;   // rowoff<24b, deg<8b
        dinv[base_node + t] = rsqrtf(1.0f + (float)dg);
    }
}

// standalone GEMM for layers 2/3 (dinv ready -> scaled epilogue, round-0 exact)
__global__ __launch_bounds__(256, 2) void gemm_kernel(const void* __restrict__ xin,
                                                      const unsigned short* __restrict__ wt,
                                                      const float* __restrict__ dinv,
                                                      unsigned int* __restrict__ hb) {
    const int wave = blockIdx.x * 4 + (threadIdx.x >> 6);
    gemm_body<false, true>(wave, xin, wt, dinv, hb);
}

// ---------------- aggregation (layers 2/3): round-0 byte-identical -----------
// out[d] = relu( dv*(hs[d] + sum_e hs[src_e]) + b ); hs pre-scaled in GEMM.
// One node per wave, 4 waves/block, info-addressed compact rows.

template <bool BF16OUT>
__global__ __launch_bounds__(256) void aggregate_kernel(const unsigned int* __restrict__ hb,
                                                        const int* __restrict__ csr,
                                                        const int* __restrict__ info,
                                                        const float* __restrict__ dinv,
                                                        const float2* __restrict__ bias2,
                                                        void* __restrict__ outp) {
    const int d = blockIdx.x * 4 + (threadIdx.x >> 6);
    const int j = threadIdx.x & 63;     // lane
    const int ifo = info[d];
    int e = ifo >> 8;
    const int end = e + (((ifo & 255) + 7) & ~7);
    float2 acc = bf2f2(hb[(size_t)d * 64 + j]);   // self term: hs[d]
    for (; e + 16 <= end; e += 16) {
        int4 c0 = *(const int4*)(csr + e);
        int4 c1 = *(const int4*)(csr + e + 4);
        int4 c2 = *(const int4*)(csr + e + 8);
        int4 c3 = *(const int4*)(csr + e + 12);
        unsigned int v0 = hb[(size_t)c0.x * 64 + j];
        unsigned int v1 = hb[(size_t)c0.y * 64 + j];
        unsigned int v2 = hb[(size_t)c0.z * 64 + j];
        unsigned int v3 = hb[(size_t)c0.w * 64 + j];
        unsigned int v4 = hb[(size_t)c1.x * 64 + j];
        unsigned int v5 = hb[(size_t)c1.y * 64 + j];
        unsigned int v6 = hb[(size_t)c1.z * 64 + j];
        unsigned int v7 = hb[(size_t)c1.w * 64 + j];
        unsigned int v8 = hb[(size_t)c2.x * 64 + j];
        unsigned int v9 = hb[(size_t)c2.y * 64 + j];
        unsigned int va = hb[(size_t)c2.z * 64 + j];
        unsigned int vb = hb[(size_t)c2.w * 64 + j];
        unsigned int vc = hb[(size_t)c3.x * 64 + j];
        unsigned int vd = hb[(size_t)c3.y * 64 + j];
        unsigned int ve = hb[(size_t)c3.z * 64 + j];
        unsigned int vf = hb[(size_t)c3.w * 64 + j];
        float2 f0 = bf2f2(v0), f1 = bf2f2(v1), f2 = bf2f2(v2), f3 = bf2f2(v3);
        float2 f4 = bf2f2(v4), f5 = bf2f2(v5), f6 = bf2f2(v6), f7 = bf2f2(v7);
        float2 f8 = bf2f2(v8), f9 = bf2f2(v9), fa = bf2f2(va), fb = bf2f2(vb);
        float2 fc = bf2f2(vc), fd = bf2f2(vd), fe = bf2f2(ve), ff = bf2f2(vf);
        acc.x += ((f0.x + f1.x) + (f2.x + f3.x)) + ((f4.x + f5.x) + (f6.x + f7.x)) +
                 ((f8.x + f9.x) + (fa.x + fb.x)) + ((fc.x + fd.x) + (fe.x + ff.x));
        acc.y += ((f0.y + f1.y) + (f2.y + f3.y)) + ((f4.y + f5.y) + (f6.y + f7.y)) +
                 ((f8.y + f9.y) + (fa.y + fb.y)) + ((fc.y + fd.y) + (fe.y + ff.y));
    }
    if (e < end) {  // one trailing 8-batch
        int4 c0 = *(const int4*)(csr + e);
        int4 c1 = *(const int4*)(csr + e + 4);
        unsigned int v0 = hb[(size_t)c0.x * 64 + j];
        unsigned int v1 = hb[(size_t)c0.y * 64 + j];
        unsigned int v2 = hb[(size_t)c0.z * 64 + j];
        unsigned int v3 = hb[(size_t)c0.w * 64 + j];
        unsigned int v4 = hb[(size_t)c1.x * 64 + j];
        unsigned int v5 = hb[(size_t)c1.y * 64 + j];
        unsigned int v6 = hb[(size_t)c1.z * 64 + j];
        unsigned int v7 = hb[(size_t)c1.w * 64 + j];
        float2 f0 = bf2f2(v0), f1 = bf2f2(v1), f2 = bf2f2(v2), f3 = bf2f2(v3);
        float2 f4 = bf2f2(v4), f5 = bf2f2(v5), f6 = bf2f2(v6), f7 = bf2f2(v7);
        acc.x += ((f0.x + f1.x) + (f2.x + f3.x)) + ((f4.x + f5.x) + (f6.x + f7.x));
        acc.y += ((f0.y + f1.y) + (f2.y + f3.y)) + ((f4.y + f5.y) + (f6.y + f7.y));
    }
    const float dv = dinv[d];
    float2 bb = bias2[j];
    float ox = fmaxf(dv * acc.x + bb.x, 0.0f);
    float oy = fmaxf(dv * acc.y + bb.y, 0.0f);
    if (BF16OUT) {
        ((unsigned int*)outp)[(size_t)d * 64 + j] = f2bf2(ox, oy);
    } else {
        ((float2*)outp)[(size_t)d * 64 + j] = make_float2(ox, oy);
    }
}

// ---------------- weighted aggregation (layer 1 only) ------------------------
// hb holds raw h; gather applies dinv[src] per edge (L2-resident broadcast
// loads) + dinv[d] on the self term. SEPARATE kernel name (not a template
// sibling) so its codegen can't perturb the unweighted variant's regalloc.

__global__ __launch_bounds__(256) void aggregate_w_kernel(const unsigned int* __restrict__ hb,
                                                          const int* __restrict__ csr,
                                                          const int* __restrict__ info,
                                                          const float* __restrict__ dinv,
                                                          const float2* __restrict__ bias2,
                                                          unsigned int* __restrict__ outp) {
    const int d = blockIdx.x * 4 + (threadIdx.x >> 6);
    const int j = threadIdx.x & 63;     // lane
    const int ifo = info[d];
    int e = ifo >> 8;
    const int end = e + (((ifo & 255) + 7) & ~7);
    const float dv = dinv[d];
    float2 acc;
    {
        float2 s = bf2f2(hb[(size_t)d * 64 + j]);
        acc.x = dv * s.x;
        acc.y = dv * s.y;
    }
    for (; e + 16 <= end; e += 16) {
        int4 c0 = *(const int4*)(csr + e);
        int4 c1 = *(const int4*)(csr + e + 4);
        int4 c2 = *(const int4*)(csr + e + 8);
        int4 c3 = *(const int4*)(csr + e + 12);
        unsigned int v0 = hb[(size_t)c0.x * 64 + j];
        unsigned int v1 = hb[(size_t)c0.y * 64 + j];
        unsigned int v2 = hb[(size_t)c0.z * 64 + j];
        unsigned int v3 = hb[(size_t)c0.w * 64 + j];
        unsigned int v4 = hb[(size_t)c1.x * 64 + j];
        unsigned int v5 = hb[(size_t)c1.y * 64 + j];
        unsigned int v6 = hb[(size_t)c1.z * 64 + j];
        unsigned int v7 = hb[(size_t)c1.w * 64 + j];
        unsigned int v8 = hb[(size_t)c2.x * 64 + j];
        unsigned int v9 = hb[(size_t)c2.y * 64 + j];
        unsigned int va = hb[(size_t)c2.z * 64 + j];
        unsigned int vb = hb[(size_t)c2.w * 64 + j];
        unsigned int vc = hb[(size_t)c3.x * 64 + j];
        unsigned int vd = hb[(size_t)c3.y * 64 + j];
        unsigned int ve = hb[(size_t)c3.z * 64 + j];
        unsigned int vf = hb[(size_t)c3.w * 64 + j];
        float w0 = dinv[c0.x], w1 = dinv[c0.y], w2 = dinv[c0.z], w3 = dinv[c0.w];
        float w4 = dinv[c1.x], w5 = dinv[c1.y], w6 = dinv[c1.z], w7 = dinv[c1.w];
        float w8 = dinv[c2.x], w9 = dinv[c2.y], wa = dinv[c2.z], wb = dinv[c2.w];
        float wc = dinv[c3.x], wd = dinv[c3.y], we = dinv[c3.z], wf = dinv[c3.w];
        float2 f0 = bf2f2(v0), f1 = bf2f2(v1), f2 = bf2f2(v2), f3 = bf2f2(v3);
        float2 f4 = bf2f2(v4), f5 = bf2f2(v5), f6 = bf2f2(v6), f7 = bf2f2(v7);
        float2 f8 = bf2f2(v8), f9 = bf2f2(v9), fa = bf2f2(va), fb = bf2f2(vb);
        float2 fc = bf2f2(vc), fd = bf2f2(vd), fe = bf2f2(ve), ff = bf2f2(vf);
        acc.x += ((w0 * f0.x + w1 * f1.x) + (w2 * f2.x + w3 * f3.x)) +
                 ((w4 * f4.x + w5 * f5.x) + (w6 * f6.x + w7 * f7.x)) +
                 ((w8 * f8.x + w9 * f9.x) + (wa * fa.x + wb * fb.x)) +
                 ((wc * fc.x + wd * fd.x) + (we * fe.x + wf * ff.x));
        acc.y += ((w0 * f0.y + w1 * f1.y) + (w2 * f2.y + w3 * f3.y)) +
                 ((w4 * f4.y + w5 * f5.y) + (w6 * f6.y + w7 * f7.y)) +
                 ((w8 * f8.y + w9 * f9.y) + (wa * fa.y + wb * fb.y)) +
                 ((wc * fc.y + wd * fd.y) + (we * fe.y + wf * ff.y));
    }
    if (e < end) {  // one trailing 8-batch
        int4 c0 = *(const int4*)(csr + e);
        int4 c1 = *(const int4*)(csr + e + 4);
        unsigned int v0 = hb[(size_t)c0.x * 64 + j];
        unsigned int v1 = hb[(size_t)c0.y * 64 + j];
        unsigned int v2 = hb[(size_t)c0.z * 64 + j];
        unsigned int v3 = hb[(size_t)c0.w * 64 + j];
        unsigned int v4 = hb[(size_t)c1.x * 64 + j];
        unsigned int v5 = hb[(size_t)c1.y * 64 + j];
        unsigned int v6 = hb[(size_t)c1.z * 64 + j];
        unsigned int v7 = hb[(size_t)c1.w * 64 + j];
        float w0 = dinv[c0.x], w1 = dinv[c0.y], w2 = dinv[c0.z], w3 = dinv[c0.w];
        float w4 = dinv[c1.x], w5 = dinv[c1.y], w6 = dinv[c1.z], w7 = dinv[c1.w];
        float2 f0 = bf2f2(v0), f1 = bf2f2(v1), f2 = bf2f2(v2), f3 = bf2f2(v3);
        float2 f4 = bf2f2(v4), f5 = bf2f2(v5), f6 = bf2f2(v6), f7 = bf2f2(v7);
        acc.x += ((w0 * f0.x + w1 * f1.x) + (w2 * f2.x + w3 * f3.x)) +
                 ((w4 * f4.x + w5 * f5.x) + (w6 * f6.x + w7 * f7.x));
        acc.y += ((w0 * f0.y + w1 * f1.y) + (w2 * f2.y + w3 * f3.y)) +
                 ((w4 * f4.y + w5 * f5.y) + (w6 * f6.y + w7 * f7.y));
    }
    float2 bb = bias2[j];
    float ox = fmaxf(dv * acc.x + bb.x, 0.0f);
    float oy = fmaxf(dv * acc.y + bb.y, 0.0f);
    outp[(size_t)d * 64 + j] = f2bf2(ox, oy);
}

// ---------------- launch ----------------

extern "C" void kernel_launch(void* const* d_in, const int* in_sizes, int n_in,
                              void* d_out, int out_size, void* d_ws, size_t ws_size,
                              hipStream_t stream) {
    const float* x0 = (const float*)d_in[0];
    const int* ei = (const int*)d_in[1];   // int32 on device (harness contract)
    const float* W1 = (const float*)d_in[2];
    const float* b1 = (const float*)d_in[3];
    const float* W2 = (const float*)d_in[4];
    const float* b2 = (const float*)d_in[5];
    const float* W3 = (const float*)d_in[6];
    const float* b3 = (const float*)d_in[7];
    float* out = (float*)d_out;

    char* ws = (char*)d_ws;
    size_t off = 0;
    auto alloc = [&](size_t bytes) -> void* {
        off = (off + 511) & ~(size_t)511;
        void* p = ws + off;
        off += bytes;
        return p;
    };
    unsigned int* hb = (unsigned int*)alloc(((size_t)NN + 1) * 64 * 4);   // 25.6 MB (+ zero row)
    int* csr = (int*)alloc((size_t)NSB * RCAP * sizeof(int));             // 16.8 MB compact
    uint2* buckets2 = (uint2*)alloc((size_t)NSB * SCAP * sizeof(uint2));  // 16.8 MB
    int* info = (int*)alloc((size_t)NN * sizeof(int));
    float* dinv = (float*)alloc(((size_t)NN + 1) * sizeof(float));        // + sentinel 0
    int* gcur2 = (int*)alloc(NSB * sizeof(int));
    unsigned short* wt1 = (unsigned short*)alloc(128 * 128 * 2);
    unsigned short* wt2 = (unsigned short*)alloc(128 * 128 * 2);
    unsigned short* wt3 = (unsigned short*)alloc(128 * 128 * 2);

    // bf16 activation ping buffer for layers 1-2 lives in d_out's first 25.6 MB
    unsigned int* xact = (unsigned int*)d_out;

    const int4* src4 = (const int4*)ei;          // edge_index[0]
    const int4* dst4 = (const int4*)(ei + EE);   // edge_index[1]

    // graph prep (redone every call: ws is re-poisoned)
    hipMemsetAsync(gcur2, 0, NSB * sizeof(int), stream);
    fbwt_kernel<<<WTB + 512, 256, 0, stream>>>(src4, dst4, gcur2, buckets2,
                                               W1, W2, W3, wt1, wt2, wt3, hb, dinv);
    sort3_gemm1_kernel<<<903, 256, 0, stream>>>(buckets2, gcur2, csr, info, dinv,
                                                x0, wt1, hb);
    // layer 1: raw h in hb -> weighted aggregate
    aggregate_w_kernel<<<NN / 4, 256, 0, stream>>>(hb, csr, info, dinv,
                                                   (const float2*)b1, xact);
    // layer 2: scaled GEMM epilogue -> round-0 aggregate
    gemm_kernel<<<391, 256, 0, stream>>>((const void*)xact, wt2, dinv, hb);
    aggregate_kernel<true><<<NN / 4, 256, 0, stream>>>(hb, csr, info, dinv,
                                                       (const float2*)b2, (void*)xact);
    // layer 3
    gemm_kernel<<<391, 256, 0, stream>>>((const void*)xact, wt3, dinv, hb);
    aggregate_kernel<false><<<NN / 4, 256, 0, stream>>>(hb, csr, info, dinv,
                                                        (const float2*)b3, (void*)out);
}